// Round 1
// baseline (656.103 us; speedup 1.0000x reference)
//
#include <hip/hip_runtime.h>

// ============================================================================
// LeNet+MoE forward, bf16 MFMA pipeline. R3: conv occupancy 2->4 waves/SIMD.
//  K1 prep: repack weights to bf16 MFMA B-operand layouts (every launch).
//  K2 conv: per-image wave: conv1+relu+pool -> conv2+relu+pool -> h2 (ws, bf16)
//           X rows padded to 36 shorts (72B = 18-bank stride, full 32-bank
//           coverage per q-group); H1 rows padded to 20 shorts (40B = 10-bank
//           stride). h2 written via LDS restage -> coalesced dword stores.
//           R3: B2 fragments no longer VGPR-resident (were 128 VGPRs) -- they
//           are re-loaded per ks-step from L1/L2 (same addrs for all blocks),
//           dropping peak live regs under 128 => __launch_bounds__(256,4)
//           => 4 blocks/CU (LDS 4x34.4KB=137KB), 16 waves/CU.
//  K3 fc  : barrier-free; one wave owns 16 images for the whole FC stack.
// ws layout (needs ~26.5 MB):
//   [0)            h2  [32768][400] bf16
//   [26214400)     B1pack [4][4][16][32] bf16
//   [26230784)     B2pack [4][8][16][32] bf16
//   [26263552)     F1p [128][416] bf16
//   [26370048)     F2p [96][128] bf16
//   [26394624)     EGp [176][96] bf16
//   [26428416)     F4p [16][96] bf16
//   [26431488)     fc1_b pad [128] f32
//   [26432000)     fc2_b pad [96] f32
//   [26432384)     fc4_b pad [16] f32
// ============================================================================

typedef unsigned int u32;
typedef unsigned short u16;
typedef __attribute__((ext_vector_type(8))) short short8;
typedef __attribute__((ext_vector_type(4))) short short4v;
typedef __attribute__((ext_vector_type(4))) float f32x4;

#define OFF_H2  0
#define OFF_B1  26214400
#define OFF_B2  26230784
#define OFF_F1  26263552
#define OFF_F2  26370048
#define OFF_EG  26394624
#define OFF_F4  26428416
#define OFF_B1P 26431488
#define OFF_B2P 26432000
#define OFF_B4P 26432384

static __device__ __forceinline__ u16 f2bf(float f) {
  u32 u = __float_as_uint(f);
  u += 0x7fffu + ((u >> 16) & 1u);   // RNE; inputs are finite
  return (u16)(u >> 16);
}
static __device__ __forceinline__ float bf2f(u16 h) {
  return __uint_as_float(((u32)h) << 16);
}

static __device__ __forceinline__ f32x4 MFMA(short8 a, short8 b, f32x4 c) {
  return __builtin_amdgcn_mfma_f32_16x16x32_bf16(a, b, c, 0, 0, 0);
}

static __device__ __forceinline__ f32x4 zero4() {
  f32x4 z = {0.f, 0.f, 0.f, 0.f};
  return z;
}

// ---------------------------------------------------------------------------
// K1: weight prep (unchanged — correct)
// ---------------------------------------------------------------------------
__global__ void prep_kernel(const float* c1w, const float* c2w,
                            const float* f1w, const float* f2w,
                            const float* gw, const float* ew, const float* f4w,
                            const float* f1b, const float* f2b, const float* f4b,
                            u16* B1, u16* B2, u16* F1, u16* F2, u16* EG, u16* F4,
                            float* b1p, float* b2p, float* b4p) {
  const int total = 108784;
  for (int i = blockIdx.x * blockDim.x + threadIdx.x; i < total;
       i += gridDim.x * blockDim.x) {
    if (i < 8192) {                       // B1pack [s][ks][n][32]
      int k1 = i & 31, n = (i >> 5) & 15, ks = (i >> 9) & 3, s = i >> 11;
      int o = ks * 4 + (k1 >> 3), j = k1 & 7;
      int dy = o / 3, ci = o - dy * 3, dx = j - s;
      float v = 0.f;
      if (n < 6 && o < 15 && dx >= 0 && dx < 5)
        v = c1w[((n * 3 + ci) * 5 + dy) * 5 + dx];
      B1[i] = f2bf(v);
    } else if (i < 24576) {               // B2pack [s][ks][n][32]
      int t = i - 8192;
      int k1 = t & 31, n = (t >> 5) & 15, ks = (t >> 9) & 7, s = t >> 12;
      int o = ks * 4 + (k1 >> 3), j = k1 & 7;
      int dy = o / 6, ci = o - dy * 6, dx = j - s;
      float v = 0.f;
      if (o < 30 && dx >= 0 && dx < 5)
        v = c2w[((n * 6 + ci) * 5 + dy) * 5 + dx];
      B2[t] = f2bf(v);
    } else if (i < 77824) {               // F1p [128][416]
      int t = i - 24576;
      int n = t / 416, k = t - n * 416;
      float v = (n < 120 && k < 400) ? f1w[n * 400 + k] : 0.f;
      F1[t] = f2bf(v);
    } else if (i < 90112) {               // F2p [96][128]
      int t = i - 77824;
      int n = t >> 7, k = t & 127;
      float v = (n < 84 && k < 120) ? f2w[n * 120 + k] : 0.f;
      F2[t] = f2bf(v);
    } else if (i < 107008) {              // EGp [176][96]
      int t = i - 90112;
      int n = t / 96, k = t - n * 96;
      float v = 0.f;
      if (k < 84) {
        if (n < 84)       v = ew[k * 84 + n];                 // expert0
        else if (n < 168) v = ew[7056 + k * 84 + (n - 84)];   // expert1
        else if (n == 168) v = gw[k * 2];
        else if (n == 169) v = gw[k * 2 + 1];
      }
      EG[t] = f2bf(v);
    } else if (i < 108544) {              // F4p [16][96]
      int t = i - 107008;
      int n = t / 96, k = t - n * 96;
      float v = (n < 10 && k < 84) ? f4w[n * 84 + k] : 0.f;
      F4[t] = f2bf(v);
    } else if (i < 108672) {
      int t = i - 108544; b1p[t] = (t < 120) ? f1b[t] : 0.f;
    } else if (i < 108768) {
      int t = i - 108672; b2p[t] = (t < 84) ? f2b[t] : 0.f;
    } else {
      int t = i - 108768; b4p[t] = (t < 10) ? f4b[t] : 0.f;
    }
  }
}

// ---------------------------------------------------------------------------
// K2: fused conv1+pool+conv2+pool, one wave per image
//   X  layout: [ci][y][36 shorts]  (72B rows: 18-bank stride, conflict-free)
//   H1 layout: [co][py][20 shorts] (40B rows: 10-bank stride, conflict-free)
// ---------------------------------------------------------------------------
#define XSTR 36
#define H1STR 20
__global__ __launch_bounds__(256, 4)
void conv_kernel(const float* __restrict__ x, const float* __restrict__ c1b,
                 const float* __restrict__ c2b,
                 const u16* __restrict__ B1g, const u16* __restrict__ B2g,
                 u16* __restrict__ h2g) {
  __shared__ __align__(16) short xs[4][3 * 32 * XSTR];   // 6912B/wave
  __shared__ __align__(16) short h1s[4][6 * 14 * H1STR]; // 3360B/wave

  const int w = threadIdx.x >> 6;
  const int lane = threadIdx.x & 63;
  const int q = lane >> 4;
  const int mc = lane & 15;
  const int img = blockIdx.x * 4 + w;
  short* X = xs[w];
  short* H1 = h1s[w];

  // zero h1 (pad cols must be zero for conv2 A reads)
  for (int i = lane; i < 6 * 14 * H1STR / 2; i += 64) ((u32*)H1)[i] = 0;

  // stage x: fp32 global -> bf16 LDS (padded rows)
  const float4* xg = (const float4*)(x + (size_t)img * 3072);
#pragma unroll
  for (int i = 0; i < 12; i++) {
    float4 v = xg[i * 64 + lane];
    short4v b;
    b.x = (short)f2bf(v.x); b.y = (short)f2bf(v.y);
    b.z = (short)f2bf(v.z); b.w = (short)f2bf(v.w);
    int idx = i * 256 + lane * 4;
    int c = idx & 31, r = idx >> 5;          // r = ci*32 + y
    *(short4v*)&X[r * XSTR + c] = b;
  }

  const float b1v = (mc < 6) ? c1b[mc] : 0.f;
  const float b2v = c2b[mc];

  // conv1 B frags resident in VGPRs: [ks][s]  (64 VGPRs, dead before conv2)
  short8 B1f[4][4];
  {
    const short8* Bv = (const short8*)B1g;
#pragma unroll
    for (int s = 0; s < 4; s++)
#pragma unroll
      for (int ks = 0; ks < 4; ks++)
        B1f[ks][s] = Bv[((s * 4 + ks) * 16 + mc) * 4 + q];
  }

  // ---- conv1 + relu + pool -> H1 ----
#pragma unroll
  for (int mt = 0; mt < 2; mt++) {
#pragma unroll
    for (int a = 0; a < 7; a++) {
      f32x4 acc0 = zero4(), acc1 = zero4(), acc2 = zero4(), acc3 = zero4();
#pragma unroll
      for (int ks = 0; ks < 4; ks++) {
        int o = ks * 4 + q;
        int dy = o / 3, ci = o - dy * 3;
        int y = mt * 16 + mc + dy;
        if (y > 31) y = 31;                 // discarded rows only; B is zero
        int base = (ci * 32 + y) * XSTR + a * 4;
        short4v lo = *(const short4v*)&X[base];
        short4v hi = *(const short4v*)&X[base + 4];
        short8 A = __builtin_shufflevector(lo, hi, 0, 1, 2, 3, 4, 5, 6, 7);
        acc0 = MFMA(A, B1f[ks][0], acc0);
        acc1 = MFMA(A, B1f[ks][1], acc1);
        acc2 = MFMA(A, B1f[ks][2], acc2);
        acc3 = MFMA(A, B1f[ks][3], acc3);
      }
#pragma unroll
      for (int rp = 0; rp < 2; rp++) {
        if (mt == 1 && q == 3) continue;    // oy >= 28 invalid
        int py = mt * 8 + q * 2 + rp;
        float v0 = fmaxf(fmaxf(acc0[2 * rp], acc0[2 * rp + 1]),
                         fmaxf(acc1[2 * rp], acc1[2 * rp + 1]));
        float v1 = fmaxf(fmaxf(acc2[2 * rp], acc2[2 * rp + 1]),
                         fmaxf(acc3[2 * rp], acc3[2 * rp + 1]));
        float p0 = fmaxf(v0 + b1v, 0.f);
        float p1 = fmaxf(v1 + b1v, 0.f);
        if (mc < 6) {
          u32 pk = ((u32)f2bf(p1) << 16) | (u32)f2bf(p0);
          *(u32*)&H1[(mc * 14 + py) * H1STR + a * 2] = pk;
        }
      }
    }
  }

  // ---- conv2 + relu + pool ----
  // R3: B2 frags loaded per ks-step (L1/L2-hit; identical addrs across all
  // blocks) instead of 128 resident VGPRs. Keeps peak live regs < 128.
  f32x4 a2[10];
#pragma unroll
  for (int i = 0; i < 10; i++) a2[i] = zero4();

  {
    const short8* Bv = (const short8*)B2g;
#pragma unroll
    for (int ks = 0; ks < 8; ks++) {
      int o = ks * 4 + q;
      int dy = o / 6, ci = o - dy * 6;
      int y = mc + dy;
      if (y > 13) y = 13;                   // discarded rows only
      int base = (ci * 14 + y) * H1STR;
      short4v c0 = *(const short4v*)&H1[base];
      short4v c1 = *(const short4v*)&H1[base + 4];
      short4v c2 = *(const short4v*)&H1[base + 8];
      short4v c3 = *(const short4v*)&H1[base + 12];
      short8 A0 = __builtin_shufflevector(c0, c1, 0, 1, 2, 3, 4, 5, 6, 7);
      short8 A1 = __builtin_shufflevector(c1, c2, 0, 1, 2, 3, 4, 5, 6, 7);
      short8 A2 = __builtin_shufflevector(c2, c3, 0, 1, 2, 3, 4, 5, 6, 7);
      short8 Bs0 = Bv[((0 * 8 + ks) * 16 + mc) * 4 + q];
      short8 Bs1 = Bv[((1 * 8 + ks) * 16 + mc) * 4 + q];
      short8 Bs2 = Bv[((2 * 8 + ks) * 16 + mc) * 4 + q];
      short8 Bs3 = Bv[((3 * 8 + ks) * 16 + mc) * 4 + q];
      a2[0] = MFMA(A0, Bs0, a2[0]);
      a2[1] = MFMA(A0, Bs1, a2[1]);
      a2[2] = MFMA(A0, Bs2, a2[2]);
      a2[3] = MFMA(A0, Bs3, a2[3]);
      a2[4] = MFMA(A1, Bs0, a2[4]);
      a2[5] = MFMA(A1, Bs1, a2[5]);
      a2[6] = MFMA(A1, Bs2, a2[6]);
      a2[7] = MFMA(A1, Bs3, a2[7]);
      a2[8] = MFMA(A2, Bs0, a2[8]);
      a2[9] = MFMA(A2, Bs1, a2[9]);
    }
  }

  // epilogue: relu+pool into LDS (reuse X region; x data is dead), then
  // coalesced dword store of the 800B h2 row.
#pragma unroll
  for (int a = 0; a < 3; a++) {
#pragma unroll
    for (int sp = 0; sp < 2; sp++) {
      if (a == 2 && sp == 1) continue;
      int px = a * 2 + sp;
      int ia = a * 4 + sp * 2;
#pragma unroll
      for (int rp = 0; rp < 2; rp++) {
        int oy = q * 4 + rp * 2;
        if (oy > 8) continue;
        int py = q * 2 + rp;
        float v = fmaxf(fmaxf(a2[ia][2 * rp], a2[ia][2 * rp + 1]),
                        fmaxf(a2[ia + 1][2 * rp], a2[ia + 1][2 * rp + 1]));
        float p = fmaxf(v + b2v, 0.f);
        X[mc * 25 + py * 5 + px] = (short)f2bf(p);
      }
    }
  }
  __asm__ volatile("s_waitcnt lgkmcnt(0)" ::: "memory");
  {
    const u32* Xu = (const u32*)X;
    u32* dst = (u32*)(h2g + (size_t)img * 400);
    for (int i = lane; i < 200; i += 64) dst[i] = Xu[i];
  }
}

// ---------------------------------------------------------------------------
// K3: FC stack, barrier-free: one wave owns 16 images end-to-end.
// Per-wave LDS (u16 units, 13440B): h3[16][136] @0, h4/h5[16][104] @2176,
// ys[16][176] @3840, probs (16 x float2) @6656.
// ---------------------------------------------------------------------------
#define FCW 6720
__global__ __launch_bounds__(256, 2)
void fc_kernel(const u16* __restrict__ h2g, const u16* __restrict__ F1,
               const u16* __restrict__ F2, const u16* __restrict__ EG,
               const u16* __restrict__ F4, const float* __restrict__ b1p,
               const float* __restrict__ b2p, const float* __restrict__ b4p,
               const float* __restrict__ eb, float* __restrict__ outp) {
  __shared__ __align__(16) u16 fcl[4][FCW];

  const int t = threadIdx.x;
  const int w = t >> 6, lane = t & 63, q = lane >> 4, mc = lane & 15;
  const size_t ib = (size_t)blockIdx.x * 64 + (size_t)w * 16;

  u16* h3 = fcl[w];            // [16][136]
  u16* h4 = fcl[w] + 2176;     // [16][104] (also h5 later)
  u16* ys = fcl[w] + 3840;     // [16][176]
  float2* probs = (float2*)(fcl[w] + 6656);

  // ---- fc1: A straight from global h2 (64B-granular), 8 n-tiles ----
  {
    short8 Af[13];
    const u16* arow = h2g + (ib + mc) * 400 + q * 8;
#pragma unroll
    for (int ks = 0; ks < 13; ks++)
      Af[ks] = *(const short8*)(arow + ks * 32);   // ks=12,q>=2 reads junk * B=0
    const short8* Bv = (const short8*)F1;
#pragma unroll
    for (int nt = 0; nt < 8; nt++) {
      f32x4 acc = zero4();
#pragma unroll
      for (int ks = 0; ks < 13; ks++)
        acc = MFMA(Af[ks], Bv[(nt * 16 + mc) * 52 + ks * 4 + q], acc);
      int n = nt * 16 + mc;
      float bias = b1p[n];
#pragma unroll
      for (int r = 0; r < 4; r++)
        h3[(q * 4 + r) * 136 + n] = f2bf(fmaxf(acc[r] + bias, 0.f));
    }
  }
  __asm__ volatile("s_waitcnt lgkmcnt(0)" ::: "memory");

  // ---- fc2: [16,128] x [128,96] ----
  {
    short8 Af[4];
#pragma unroll
    for (int ks = 0; ks < 4; ks++)
      Af[ks] = *(const short8*)&h3[mc * 136 + ks * 32 + q * 8];
    const short8* Bv = (const short8*)F2;
#pragma unroll
    for (int nt = 0; nt < 6; nt++) {
      f32x4 acc = zero4();
#pragma unroll
      for (int ks = 0; ks < 4; ks++)
        acc = MFMA(Af[ks], Bv[(nt * 16 + mc) * 16 + ks * 4 + q], acc);
      int n = nt * 16 + mc;
      float bias = b2p[n];
#pragma unroll
      for (int r = 0; r < 4; r++)
        h4[(q * 4 + r) * 104 + n] = f2bf(fmaxf(acc[r] + bias, 0.f));
    }
  }
  __asm__ volatile("s_waitcnt lgkmcnt(0)" ::: "memory");

  // ---- experts + gate: [16,96] x [96,176] ----
  {
    short8 Af[3];
#pragma unroll
    for (int ks = 0; ks < 3; ks++)
      Af[ks] = *(const short8*)&h4[mc * 104 + ks * 32 + q * 8];
    const short8* Bv = (const short8*)EG;
#pragma unroll
    for (int nt = 0; nt < 11; nt++) {
      f32x4 acc = zero4();
#pragma unroll
      for (int ks = 0; ks < 3; ks++)
        acc = MFMA(Af[ks], Bv[(nt * 16 + mc) * 12 + ks * 4 + q], acc);
      int n = nt * 16 + mc;
#pragma unroll
      for (int r = 0; r < 4; r++)
        ys[(q * 4 + r) * 176 + n] = f2bf(acc[r]);
    }
  }
  __asm__ volatile("s_waitcnt lgkmcnt(0)" ::: "memory");

  // softmax over gate logits (cols 168,169), one lane per image
  if (lane < 16) {
    float l0 = bf2f(ys[lane * 176 + 168]);
    float l1 = bf2f(ys[lane * 176 + 169]);
    float m = fmaxf(l0, l1);
    float e0 = __expf(l0 - m), e1 = __expf(l1 - m);
    float s = e0 + e1;
    probs[lane] = make_float2(e0 / s, e1 / s);
  }
  __asm__ volatile("s_waitcnt lgkmcnt(0)" ::: "memory");

  // combine into h5 (reuse h4 region), pad cols 84..95 = 0
  for (int i = lane; i < 16 * 84; i += 64) {
    int img = i / 84, h = i - img * 84;
    float2 p = probs[img];
    float y0 = bf2f(ys[img * 176 + h]) + eb[h];
    float y1 = bf2f(ys[img * 176 + 84 + h]) + eb[84 + h];
    h4[img * 104 + h] = f2bf(p.x * y0 + p.y * y1);
  }
  for (int i = lane; i < 16 * 12; i += 64)
    h4[(i / 12) * 104 + 84 + (i % 12)] = 0;
  __asm__ volatile("s_waitcnt lgkmcnt(0)" ::: "memory");

  // ---- fc4: [16,96] x [96,16] ----
  {
    short8 Af[3];
#pragma unroll
    for (int ks = 0; ks < 3; ks++)
      Af[ks] = *(const short8*)&h4[mc * 104 + ks * 32 + q * 8];
    const short8* Bv = (const short8*)F4;
    f32x4 acc = zero4();
#pragma unroll
    for (int ks = 0; ks < 3; ks++)
      acc = MFMA(Af[ks], Bv[mc * 12 + ks * 4 + q], acc);
    if (mc < 10) {
      float bias = b4p[mc];
#pragma unroll
      for (int r = 0; r < 4; r++)
        outp[(ib + q * 4 + r) * 10 + mc] = acc[r] + bias;
    }
  }
}

// ---------------------------------------------------------------------------
extern "C" void kernel_launch(void* const* d_in, const int* in_sizes, int n_in,
                              void* d_out, int out_size, void* d_ws, size_t ws_size,
                              hipStream_t stream) {
  const float* x   = (const float*)d_in[0];
  const float* c1w = (const float*)d_in[1];
  const float* c1b = (const float*)d_in[2];
  const float* c2w = (const float*)d_in[3];
  const float* c2b = (const float*)d_in[4];
  const float* f1w = (const float*)d_in[5];
  const float* f1b = (const float*)d_in[6];
  const float* f2w = (const float*)d_in[7];
  const float* f2b = (const float*)d_in[8];
  const float* gw  = (const float*)d_in[9];
  const float* ew  = (const float*)d_in[10];
  const float* ebp = (const float*)d_in[11];
  const float* f4w = (const float*)d_in[12];
  const float* f4b = (const float*)d_in[13];
  float* outp = (float*)d_out;

  char* ws = (char*)d_ws;
  u16* H2 = (u16*)(ws + OFF_H2);
  u16* B1 = (u16*)(ws + OFF_B1);
  u16* B2 = (u16*)(ws + OFF_B2);
  u16* F1 = (u16*)(ws + OFF_F1);
  u16* F2 = (u16*)(ws + OFF_F2);
  u16* EG = (u16*)(ws + OFF_EG);
  u16* F4 = (u16*)(ws + OFF_F4);
  float* b1p = (float*)(ws + OFF_B1P);
  float* b2p = (float*)(ws + OFF_B2P);
  float* b4p = (float*)(ws + OFF_B4P);

  prep_kernel<<<128, 256, 0, stream>>>(c1w, c2w, f1w, f2w, gw, ew, f4w,
                                       f1b, f2b, f4b,
                                       B1, B2, F1, F2, EG, F4, b1p, b2p, b4p);
  conv_kernel<<<8192, 256, 0, stream>>>(x, c1b, c2b, B1, B2, H2);
  fc_kernel<<<512, 256, 0, stream>>>(H2, F1, F2, EG, F4, b1p, b2p, b4p,
                                     ebp, outp);
}

// Round 2
// 641.912 us; speedup vs baseline: 1.0221x; 1.0221x over previous
//
#include <hip/hip_runtime.h>

// ============================================================================
// LeNet+MoE forward, bf16 MFMA pipeline. R4 = revert to R2 (best measured,
// 640.8 us). R3's occupancy experiment (B2 reload from L2, bounds(256,4))
// regressed 2.4%: conv was already BW-bound at 2 blocks/CU (required
// in-flight ~10KB/CU << 8 waves' stage traffic), and the per-ks B2 reloads
// added L2 latency to conv2's critical path.
//  K1 prep: repack weights to bf16 MFMA B-operand layouts (every launch).
//  K2 conv: per-image wave: conv1+relu+pool -> conv2+relu+pool -> h2 (ws, bf16)
//           X rows padded to 36 shorts (72B = 18-bank stride, full 32-bank
//           coverage per q-group); H1 rows padded to 20 shorts (40B = 10-bank
//           stride). h2 written via LDS restage -> coalesced dword stores.
//  K3 fc  : barrier-free; one wave owns 16 images for the whole FC stack.
// ws layout (needs ~26.5 MB):
//   [0)            h2  [32768][400] bf16
//   [26214400)     B1pack [4][4][16][32] bf16
//   [26230784)     B2pack [4][8][16][32] bf16
//   [26263552)     F1p [128][416] bf16
//   [26370048)     F2p [96][128] bf16
//   [26394624)     EGp [176][96] bf16
//   [26428416)     F4p [16][96] bf16
//   [26431488)     fc1_b pad [128] f32
//   [26432000)     fc2_b pad [96] f32
//   [26432384)     fc4_b pad [16] f32
// ============================================================================

typedef unsigned int u32;
typedef unsigned short u16;
typedef __attribute__((ext_vector_type(8))) short short8;
typedef __attribute__((ext_vector_type(4))) short short4v;
typedef __attribute__((ext_vector_type(4))) float f32x4;

#define OFF_H2  0
#define OFF_B1  26214400
#define OFF_B2  26230784
#define OFF_F1  26263552
#define OFF_F2  26370048
#define OFF_EG  26394624
#define OFF_F4  26428416
#define OFF_B1P 26431488
#define OFF_B2P 26432000
#define OFF_B4P 26432384

static __device__ __forceinline__ u16 f2bf(float f) {
  u32 u = __float_as_uint(f);
  u += 0x7fffu + ((u >> 16) & 1u);   // RNE; inputs are finite
  return (u16)(u >> 16);
}
static __device__ __forceinline__ float bf2f(u16 h) {
  return __uint_as_float(((u32)h) << 16);
}

static __device__ __forceinline__ f32x4 MFMA(short8 a, short8 b, f32x4 c) {
  return __builtin_amdgcn_mfma_f32_16x16x32_bf16(a, b, c, 0, 0, 0);
}

static __device__ __forceinline__ f32x4 zero4() {
  f32x4 z = {0.f, 0.f, 0.f, 0.f};
  return z;
}

// ---------------------------------------------------------------------------
// K1: weight prep (unchanged — correct)
// ---------------------------------------------------------------------------
__global__ void prep_kernel(const float* c1w, const float* c2w,
                            const float* f1w, const float* f2w,
                            const float* gw, const float* ew, const float* f4w,
                            const float* f1b, const float* f2b, const float* f4b,
                            u16* B1, u16* B2, u16* F1, u16* F2, u16* EG, u16* F4,
                            float* b1p, float* b2p, float* b4p) {
  const int total = 108784;
  for (int i = blockIdx.x * blockDim.x + threadIdx.x; i < total;
       i += gridDim.x * blockDim.x) {
    if (i < 8192) {                       // B1pack [s][ks][n][32]
      int k1 = i & 31, n = (i >> 5) & 15, ks = (i >> 9) & 3, s = i >> 11;
      int o = ks * 4 + (k1 >> 3), j = k1 & 7;
      int dy = o / 3, ci = o - dy * 3, dx = j - s;
      float v = 0.f;
      if (n < 6 && o < 15 && dx >= 0 && dx < 5)
        v = c1w[((n * 3 + ci) * 5 + dy) * 5 + dx];
      B1[i] = f2bf(v);
    } else if (i < 24576) {               // B2pack [s][ks][n][32]
      int t = i - 8192;
      int k1 = t & 31, n = (t >> 5) & 15, ks = (t >> 9) & 7, s = t >> 12;
      int o = ks * 4 + (k1 >> 3), j = k1 & 7;
      int dy = o / 6, ci = o - dy * 6, dx = j - s;
      float v = 0.f;
      if (o < 30 && dx >= 0 && dx < 5)
        v = c2w[((n * 6 + ci) * 5 + dy) * 5 + dx];
      B2[t] = f2bf(v);
    } else if (i < 77824) {               // F1p [128][416]
      int t = i - 24576;
      int n = t / 416, k = t - n * 416;
      float v = (n < 120 && k < 400) ? f1w[n * 400 + k] : 0.f;
      F1[t] = f2bf(v);
    } else if (i < 90112) {               // F2p [96][128]
      int t = i - 77824;
      int n = t >> 7, k = t & 127;
      float v = (n < 84 && k < 120) ? f2w[n * 120 + k] : 0.f;
      F2[t] = f2bf(v);
    } else if (i < 107008) {              // EGp [176][96]
      int t = i - 90112;
      int n = t / 96, k = t - n * 96;
      float v = 0.f;
      if (k < 84) {
        if (n < 84)       v = ew[k * 84 + n];                 // expert0
        else if (n < 168) v = ew[7056 + k * 84 + (n - 84)];   // expert1
        else if (n == 168) v = gw[k * 2];
        else if (n == 169) v = gw[k * 2 + 1];
      }
      EG[t] = f2bf(v);
    } else if (i < 108544) {              // F4p [16][96]
      int t = i - 107008;
      int n = t / 96, k = t - n * 96;
      float v = (n < 10 && k < 84) ? f4w[n * 84 + k] : 0.f;
      F4[t] = f2bf(v);
    } else if (i < 108672) {
      int t = i - 108544; b1p[t] = (t < 120) ? f1b[t] : 0.f;
    } else if (i < 108768) {
      int t = i - 108672; b2p[t] = (t < 84) ? f2b[t] : 0.f;
    } else {
      int t = i - 108768; b4p[t] = (t < 10) ? f4b[t] : 0.f;
    }
  }
}

// ---------------------------------------------------------------------------
// K2: fused conv1+pool+conv2+pool, one wave per image
//   X  layout: [ci][y][36 shorts]  (72B rows: 18-bank stride, conflict-free)
//   H1 layout: [co][py][20 shorts] (40B rows: 10-bank stride, conflict-free)
// ---------------------------------------------------------------------------
#define XSTR 36
#define H1STR 20
__global__ __launch_bounds__(256, 2)
void conv_kernel(const float* __restrict__ x, const float* __restrict__ c1b,
                 const float* __restrict__ c2b,
                 const u16* __restrict__ B1g, const u16* __restrict__ B2g,
                 u16* __restrict__ h2g) {
  __shared__ __align__(16) short xs[4][3 * 32 * XSTR];   // 6912B/wave
  __shared__ __align__(16) short h1s[4][6 * 14 * H1STR]; // 3360B/wave

  const int w = threadIdx.x >> 6;
  const int lane = threadIdx.x & 63;
  const int q = lane >> 4;
  const int mc = lane & 15;
  const int img = blockIdx.x * 4 + w;
  short* X = xs[w];
  short* H1 = h1s[w];

  // zero h1 (pad cols must be zero for conv2 A reads)
  for (int i = lane; i < 6 * 14 * H1STR / 2; i += 64) ((u32*)H1)[i] = 0;

  // stage x: fp32 global -> bf16 LDS (padded rows)
  const float4* xg = (const float4*)(x + (size_t)img * 3072);
#pragma unroll
  for (int i = 0; i < 12; i++) {
    float4 v = xg[i * 64 + lane];
    short4v b;
    b.x = (short)f2bf(v.x); b.y = (short)f2bf(v.y);
    b.z = (short)f2bf(v.z); b.w = (short)f2bf(v.w);
    int idx = i * 256 + lane * 4;
    int c = idx & 31, r = idx >> 5;          // r = ci*32 + y
    *(short4v*)&X[r * XSTR + c] = b;
  }

  const float b1v = (mc < 6) ? c1b[mc] : 0.f;
  const float b2v = c2b[mc];

  // conv1 B frags resident in VGPRs: [ks][s]
  short8 B1f[4][4];
  {
    const short8* Bv = (const short8*)B1g;
#pragma unroll
    for (int s = 0; s < 4; s++)
#pragma unroll
      for (int ks = 0; ks < 4; ks++)
        B1f[ks][s] = Bv[((s * 4 + ks) * 16 + mc) * 4 + q];
  }

  // ---- conv1 + relu + pool -> H1 ----
#pragma unroll
  for (int mt = 0; mt < 2; mt++) {
#pragma unroll
    for (int a = 0; a < 7; a++) {
      f32x4 acc0 = zero4(), acc1 = zero4(), acc2 = zero4(), acc3 = zero4();
#pragma unroll
      for (int ks = 0; ks < 4; ks++) {
        int o = ks * 4 + q;
        int dy = o / 3, ci = o - dy * 3;
        int y = mt * 16 + mc + dy;
        if (y > 31) y = 31;                 // discarded rows only; B is zero
        int base = (ci * 32 + y) * XSTR + a * 4;
        short4v lo = *(const short4v*)&X[base];
        short4v hi = *(const short4v*)&X[base + 4];
        short8 A = __builtin_shufflevector(lo, hi, 0, 1, 2, 3, 4, 5, 6, 7);
        acc0 = MFMA(A, B1f[ks][0], acc0);
        acc1 = MFMA(A, B1f[ks][1], acc1);
        acc2 = MFMA(A, B1f[ks][2], acc2);
        acc3 = MFMA(A, B1f[ks][3], acc3);
      }
#pragma unroll
      for (int rp = 0; rp < 2; rp++) {
        if (mt == 1 && q == 3) continue;    // oy >= 28 invalid
        int py = mt * 8 + q * 2 + rp;
        float v0 = fmaxf(fmaxf(acc0[2 * rp], acc0[2 * rp + 1]),
                         fmaxf(acc1[2 * rp], acc1[2 * rp + 1]));
        float v1 = fmaxf(fmaxf(acc2[2 * rp], acc2[2 * rp + 1]),
                         fmaxf(acc3[2 * rp], acc3[2 * rp + 1]));
        float p0 = fmaxf(v0 + b1v, 0.f);
        float p1 = fmaxf(v1 + b1v, 0.f);
        if (mc < 6) {
          u32 pk = ((u32)f2bf(p1) << 16) | (u32)f2bf(p0);
          *(u32*)&H1[(mc * 14 + py) * H1STR + a * 2] = pk;
        }
      }
    }
  }

  // conv2 B frags resident in VGPRs: [ks][s]
  short8 B2f[8][4];
  {
    const short8* Bv = (const short8*)B2g;
#pragma unroll
    for (int s = 0; s < 4; s++)
#pragma unroll
      for (int ks = 0; ks < 8; ks++)
        B2f[ks][s] = Bv[((s * 8 + ks) * 16 + mc) * 4 + q];
  }

  // ---- conv2 + relu + pool ----
  f32x4 a2[10];
#pragma unroll
  for (int i = 0; i < 10; i++) a2[i] = zero4();

#pragma unroll
  for (int ks = 0; ks < 8; ks++) {
    int o = ks * 4 + q;
    int dy = o / 6, ci = o - dy * 6;
    int y = mc + dy;
    if (y > 13) y = 13;                     // discarded rows only
    int base = (ci * 14 + y) * H1STR;
    short4v c0 = *(const short4v*)&H1[base];
    short4v c1 = *(const short4v*)&H1[base + 4];
    short4v c2 = *(const short4v*)&H1[base + 8];
    short4v c3 = *(const short4v*)&H1[base + 12];
    short8 A0 = __builtin_shufflevector(c0, c1, 0, 1, 2, 3, 4, 5, 6, 7);
    short8 A1 = __builtin_shufflevector(c1, c2, 0, 1, 2, 3, 4, 5, 6, 7);
    short8 A2 = __builtin_shufflevector(c2, c3, 0, 1, 2, 3, 4, 5, 6, 7);
    a2[0] = MFMA(A0, B2f[ks][0], a2[0]);
    a2[1] = MFMA(A0, B2f[ks][1], a2[1]);
    a2[2] = MFMA(A0, B2f[ks][2], a2[2]);
    a2[3] = MFMA(A0, B2f[ks][3], a2[3]);
    a2[4] = MFMA(A1, B2f[ks][0], a2[4]);
    a2[5] = MFMA(A1, B2f[ks][1], a2[5]);
    a2[6] = MFMA(A1, B2f[ks][2], a2[6]);
    a2[7] = MFMA(A1, B2f[ks][3], a2[7]);
    a2[8] = MFMA(A2, B2f[ks][0], a2[8]);
    a2[9] = MFMA(A2, B2f[ks][1], a2[9]);
  }

  // epilogue: relu+pool into LDS (reuse X region; x data is dead), then
  // coalesced dword store of the 800B h2 row.
#pragma unroll
  for (int a = 0; a < 3; a++) {
#pragma unroll
    for (int sp = 0; sp < 2; sp++) {
      if (a == 2 && sp == 1) continue;
      int px = a * 2 + sp;
      int ia = a * 4 + sp * 2;
#pragma unroll
      for (int rp = 0; rp < 2; rp++) {
        int oy = q * 4 + rp * 2;
        if (oy > 8) continue;
        int py = q * 2 + rp;
        float v = fmaxf(fmaxf(a2[ia][2 * rp], a2[ia][2 * rp + 1]),
                        fmaxf(a2[ia + 1][2 * rp], a2[ia + 1][2 * rp + 1]));
        float p = fmaxf(v + b2v, 0.f);
        X[mc * 25 + py * 5 + px] = (short)f2bf(p);
      }
    }
  }
  __asm__ volatile("s_waitcnt lgkmcnt(0)" ::: "memory");
  {
    const u32* Xu = (const u32*)X;
    u32* dst = (u32*)(h2g + (size_t)img * 400);
    for (int i = lane; i < 200; i += 64) dst[i] = Xu[i];
  }
}

// ---------------------------------------------------------------------------
// K3: FC stack, barrier-free: one wave owns 16 images end-to-end.
// Per-wave LDS (u16 units, 13440B): h3[16][136] @0, h4/h5[16][104] @2176,
// ys[16][176] @3840, probs (16 x float2) @6656.
// ---------------------------------------------------------------------------
#define FCW 6720
__global__ __launch_bounds__(256, 2)
void fc_kernel(const u16* __restrict__ h2g, const u16* __restrict__ F1,
               const u16* __restrict__ F2, const u16* __restrict__ EG,
               const u16* __restrict__ F4, const float* __restrict__ b1p,
               const float* __restrict__ b2p, const float* __restrict__ b4p,
               const float* __restrict__ eb, float* __restrict__ outp) {
  __shared__ __align__(16) u16 fcl[4][FCW];

  const int t = threadIdx.x;
  const int w = t >> 6, lane = t & 63, q = lane >> 4, mc = lane & 15;
  const size_t ib = (size_t)blockIdx.x * 64 + (size_t)w * 16;

  u16* h3 = fcl[w];            // [16][136]
  u16* h4 = fcl[w] + 2176;     // [16][104] (also h5 later)
  u16* ys = fcl[w] + 3840;     // [16][176]
  float2* probs = (float2*)(fcl[w] + 6656);

  // ---- fc1: A straight from global h2 (64B-granular), 8 n-tiles ----
  {
    short8 Af[13];
    const u16* arow = h2g + (ib + mc) * 400 + q * 8;
#pragma unroll
    for (int ks = 0; ks < 13; ks++)
      Af[ks] = *(const short8*)(arow + ks * 32);   // ks=12,q>=2 reads junk * B=0
    const short8* Bv = (const short8*)F1;
#pragma unroll
    for (int nt = 0; nt < 8; nt++) {
      f32x4 acc = zero4();
#pragma unroll
      for (int ks = 0; ks < 13; ks++)
        acc = MFMA(Af[ks], Bv[(nt * 16 + mc) * 52 + ks * 4 + q], acc);
      int n = nt * 16 + mc;
      float bias = b1p[n];
#pragma unroll
      for (int r = 0; r < 4; r++)
        h3[(q * 4 + r) * 136 + n] = f2bf(fmaxf(acc[r] + bias, 0.f));
    }
  }
  __asm__ volatile("s_waitcnt lgkmcnt(0)" ::: "memory");

  // ---- fc2: [16,128] x [128,96] ----
  {
    short8 Af[4];
#pragma unroll
    for (int ks = 0; ks < 4; ks++)
      Af[ks] = *(const short8*)&h3[mc * 136 + ks * 32 + q * 8];
    const short8* Bv = (const short8*)F2;
#pragma unroll
    for (int nt = 0; nt < 6; nt++) {
      f32x4 acc = zero4();
#pragma unroll
      for (int ks = 0; ks < 4; ks++)
        acc = MFMA(Af[ks], Bv[(nt * 16 + mc) * 16 + ks * 4 + q], acc);
      int n = nt * 16 + mc;
      float bias = b2p[n];
#pragma unroll
      for (int r = 0; r < 4; r++)
        h4[(q * 4 + r) * 104 + n] = f2bf(fmaxf(acc[r] + bias, 0.f));
    }
  }
  __asm__ volatile("s_waitcnt lgkmcnt(0)" ::: "memory");

  // ---- experts + gate: [16,96] x [96,176] ----
  {
    short8 Af[3];
#pragma unroll
    for (int ks = 0; ks < 3; ks++)
      Af[ks] = *(const short8*)&h4[mc * 104 + ks * 32 + q * 8];
    const short8* Bv = (const short8*)EG;
#pragma unroll
    for (int nt = 0; nt < 11; nt++) {
      f32x4 acc = zero4();
#pragma unroll
      for (int ks = 0; ks < 3; ks++)
        acc = MFMA(Af[ks], Bv[(nt * 16 + mc) * 12 + ks * 4 + q], acc);
      int n = nt * 16 + mc;
#pragma unroll
      for (int r = 0; r < 4; r++)
        ys[(q * 4 + r) * 176 + n] = f2bf(acc[r]);
    }
  }
  __asm__ volatile("s_waitcnt lgkmcnt(0)" ::: "memory");

  // softmax over gate logits (cols 168,169), one lane per image
  if (lane < 16) {
    float l0 = bf2f(ys[lane * 176 + 168]);
    float l1 = bf2f(ys[lane * 176 + 169]);
    float m = fmaxf(l0, l1);
    float e0 = __expf(l0 - m), e1 = __expf(l1 - m);
    float s = e0 + e1;
    probs[lane] = make_float2(e0 / s, e1 / s);
  }
  __asm__ volatile("s_waitcnt lgkmcnt(0)" ::: "memory");

  // combine into h5 (reuse h4 region), pad cols 84..95 = 0
  for (int i = lane; i < 16 * 84; i += 64) {
    int img = i / 84, h = i - img * 84;
    float2 p = probs[img];
    float y0 = bf2f(ys[img * 176 + h]) + eb[h];
    float y1 = bf2f(ys[img * 176 + 84 + h]) + eb[84 + h];
    h4[img * 104 + h] = f2bf(p.x * y0 + p.y * y1);
  }
  for (int i = lane; i < 16 * 12; i += 64)
    h4[(i / 12) * 104 + 84 + (i % 12)] = 0;
  __asm__ volatile("s_waitcnt lgkmcnt(0)" ::: "memory");

  // ---- fc4: [16,96] x [96,16] ----
  {
    short8 Af[3];
#pragma unroll
    for (int ks = 0; ks < 3; ks++)
      Af[ks] = *(const short8*)&h4[mc * 104 + ks * 32 + q * 8];
    const short8* Bv = (const short8*)F4;
    f32x4 acc = zero4();
#pragma unroll
    for (int ks = 0; ks < 3; ks++)
      acc = MFMA(Af[ks], Bv[mc * 12 + ks * 4 + q], acc);
    if (mc < 10) {
      float bias = b4p[mc];
#pragma unroll
      for (int r = 0; r < 4; r++)
        outp[(ib + q * 4 + r) * 10 + mc] = acc[r] + bias;
    }
  }
}

// ---------------------------------------------------------------------------
extern "C" void kernel_launch(void* const* d_in, const int* in_sizes, int n_in,
                              void* d_out, int out_size, void* d_ws, size_t ws_size,
                              hipStream_t stream) {
  const float* x   = (const float*)d_in[0];
  const float* c1w = (const float*)d_in[1];
  const float* c1b = (const float*)d_in[2];
  const float* c2w = (const float*)d_in[3];
  const float* c2b = (const float*)d_in[4];
  const float* f1w = (const float*)d_in[5];
  const float* f1b = (const float*)d_in[6];
  const float* f2w = (const float*)d_in[7];
  const float* f2b = (const float*)d_in[8];
  const float* gw  = (const float*)d_in[9];
  const float* ew  = (const float*)d_in[10];
  const float* ebp = (const float*)d_in[11];
  const float* f4w = (const float*)d_in[12];
  const float* f4b = (const float*)d_in[13];
  float* outp = (float*)d_out;

  char* ws = (char*)d_ws;
  u16* H2 = (u16*)(ws + OFF_H2);
  u16* B1 = (u16*)(ws + OFF_B1);
  u16* B2 = (u16*)(ws + OFF_B2);
  u16* F1 = (u16*)(ws + OFF_F1);
  u16* F2 = (u16*)(ws + OFF_F2);
  u16* EG = (u16*)(ws + OFF_EG);
  u16* F4 = (u16*)(ws + OFF_F4);
  float* b1p = (float*)(ws + OFF_B1P);
  float* b2p = (float*)(ws + OFF_B2P);
  float* b4p = (float*)(ws + OFF_B4P);

  prep_kernel<<<128, 256, 0, stream>>>(c1w, c2w, f1w, f2w, gw, ew, f4w,
                                       f1b, f2b, f4b,
                                       B1, B2, F1, F2, EG, F4, b1p, b2p, b4p);
  conv_kernel<<<8192, 256, 0, stream>>>(x, c1b, c2b, B1, B2, H2);
  fc_kernel<<<512, 256, 0, stream>>>(H2, F1, F2, EG, F4, b1p, b2p, b4p,
                                     ebp, outp);
}

// Round 3
// 631.501 us; speedup vs baseline: 1.0390x; 1.0165x over previous
//
#include <hip/hip_runtime.h>

// ============================================================================
// LeNet+MoE forward, bf16 MFMA pipeline. R5: conv1 row-hoisting.
//  R2/R4 baseline 641 us (incl ~500 us fixed harness poison fills).
//  R5 change (conv kernel only):
//   - conv1 A-operands: per (mt,ks) load the full 32-short X row ONCE
//     (8x ds_read_b64 -> 16 VGPRs), build the 7 overlapping a-window
//     fragments via register shuffles. LDS reads 112 -> 64 per image
//     (the a-windows previously re-read each row element ~2x per ks).
//   - H1 zeroing: only the pad dword (cols 14-15) per row is ever read
//     as garbage by conv2 -> zero 84 dwords instead of 840.
//  K1 prep: repack weights to bf16 MFMA B-operand layouts (every launch).
//  K2 conv: per-image wave: conv1+relu+pool -> conv2+relu+pool -> h2 (bf16)
//           X rows padded to 36 shorts (72B = 18-bank stride, conflict-free);
//           H1 rows padded to 20 shorts (40B = 10-bank stride).
//  K3 fc  : barrier-free; one wave owns 16 images for the whole FC stack.
// ws layout (needs ~26.5 MB):
//   [0)            h2  [32768][400] bf16
//   [26214400)     B1pack [4][4][16][32] bf16
//   [26230784)     B2pack [4][8][16][32] bf16
//   [26263552)     F1p [128][416] bf16
//   [26370048)     F2p [96][128] bf16
//   [26394624)     EGp [176][96] bf16
//   [26428416)     F4p [16][96] bf16
//   [26431488)     fc1_b pad [128] f32
//   [26432000)     fc2_b pad [96] f32
//   [26432384)     fc4_b pad [16] f32
// ============================================================================

typedef unsigned int u32;
typedef unsigned short u16;
typedef __attribute__((ext_vector_type(8))) short short8;
typedef __attribute__((ext_vector_type(4))) short short4v;
typedef __attribute__((ext_vector_type(4))) float f32x4;

#define OFF_H2  0
#define OFF_B1  26214400
#define OFF_B2  26230784
#define OFF_F1  26263552
#define OFF_F2  26370048
#define OFF_EG  26394624
#define OFF_F4  26428416
#define OFF_B1P 26431488
#define OFF_B2P 26432000
#define OFF_B4P 26432384

static __device__ __forceinline__ u16 f2bf(float f) {
  u32 u = __float_as_uint(f);
  u += 0x7fffu + ((u >> 16) & 1u);   // RNE; inputs are finite
  return (u16)(u >> 16);
}
static __device__ __forceinline__ float bf2f(u16 h) {
  return __uint_as_float(((u32)h) << 16);
}

static __device__ __forceinline__ f32x4 MFMA(short8 a, short8 b, f32x4 c) {
  return __builtin_amdgcn_mfma_f32_16x16x32_bf16(a, b, c, 0, 0, 0);
}

static __device__ __forceinline__ f32x4 zero4() {
  f32x4 z = {0.f, 0.f, 0.f, 0.f};
  return z;
}

// ---------------------------------------------------------------------------
// K1: weight prep (unchanged — correct)
// ---------------------------------------------------------------------------
__global__ void prep_kernel(const float* c1w, const float* c2w,
                            const float* f1w, const float* f2w,
                            const float* gw, const float* ew, const float* f4w,
                            const float* f1b, const float* f2b, const float* f4b,
                            u16* B1, u16* B2, u16* F1, u16* F2, u16* EG, u16* F4,
                            float* b1p, float* b2p, float* b4p) {
  const int total = 108784;
  for (int i = blockIdx.x * blockDim.x + threadIdx.x; i < total;
       i += gridDim.x * blockDim.x) {
    if (i < 8192) {                       // B1pack [s][ks][n][32]
      int k1 = i & 31, n = (i >> 5) & 15, ks = (i >> 9) & 3, s = i >> 11;
      int o = ks * 4 + (k1 >> 3), j = k1 & 7;
      int dy = o / 3, ci = o - dy * 3, dx = j - s;
      float v = 0.f;
      if (n < 6 && o < 15 && dx >= 0 && dx < 5)
        v = c1w[((n * 3 + ci) * 5 + dy) * 5 + dx];
      B1[i] = f2bf(v);
    } else if (i < 24576) {               // B2pack [s][ks][n][32]
      int t = i - 8192;
      int k1 = t & 31, n = (t >> 5) & 15, ks = (t >> 9) & 7, s = t >> 12;
      int o = ks * 4 + (k1 >> 3), j = k1 & 7;
      int dy = o / 6, ci = o - dy * 6, dx = j - s;
      float v = 0.f;
      if (o < 30 && dx >= 0 && dx < 5)
        v = c2w[((n * 6 + ci) * 5 + dy) * 5 + dx];
      B2[t] = f2bf(v);
    } else if (i < 77824) {               // F1p [128][416]
      int t = i - 24576;
      int n = t / 416, k = t - n * 416;
      float v = (n < 120 && k < 400) ? f1w[n * 400 + k] : 0.f;
      F1[t] = f2bf(v);
    } else if (i < 90112) {               // F2p [96][128]
      int t = i - 77824;
      int n = t >> 7, k = t & 127;
      float v = (n < 84 && k < 120) ? f2w[n * 120 + k] : 0.f;
      F2[t] = f2bf(v);
    } else if (i < 107008) {              // EGp [176][96]
      int t = i - 90112;
      int n = t / 96, k = t - n * 96;
      float v = 0.f;
      if (k < 84) {
        if (n < 84)       v = ew[k * 84 + n];                 // expert0
        else if (n < 168) v = ew[7056 + k * 84 + (n - 84)];   // expert1
        else if (n == 168) v = gw[k * 2];
        else if (n == 169) v = gw[k * 2 + 1];
      }
      EG[t] = f2bf(v);
    } else if (i < 108544) {              // F4p [16][96]
      int t = i - 107008;
      int n = t / 96, k = t - n * 96;
      float v = (n < 10 && k < 84) ? f4w[n * 84 + k] : 0.f;
      F4[t] = f2bf(v);
    } else if (i < 108672) {
      int t = i - 108544; b1p[t] = (t < 120) ? f1b[t] : 0.f;
    } else if (i < 108768) {
      int t = i - 108672; b2p[t] = (t < 84) ? f2b[t] : 0.f;
    } else {
      int t = i - 108768; b4p[t] = (t < 10) ? f4b[t] : 0.f;
    }
  }
}

// ---------------------------------------------------------------------------
// K2: fused conv1+pool+conv2+pool, one wave per image
//   X  layout: [ci][y][36 shorts]  (72B rows: 18-bank stride, conflict-free)
//   H1 layout: [co][py][20 shorts] (40B rows: 10-bank stride, conflict-free)
// ---------------------------------------------------------------------------
#define XSTR 36
#define H1STR 20
__global__ __launch_bounds__(256, 2)
void conv_kernel(const float* __restrict__ x, const float* __restrict__ c1b,
                 const float* __restrict__ c2b,
                 const u16* __restrict__ B1g, const u16* __restrict__ B2g,
                 u16* __restrict__ h2g) {
  __shared__ __align__(16) short xs[4][3 * 32 * XSTR];   // 6912B/wave
  __shared__ __align__(16) short h1s[4][6 * 14 * H1STR]; // 3360B/wave

  const int w = threadIdx.x >> 6;
  const int lane = threadIdx.x & 63;
  const int q = lane >> 4;
  const int mc = lane & 15;
  const int img = blockIdx.x * 4 + w;
  short* X = xs[w];
  short* H1 = h1s[w];

  // zero only H1's garbage-read pad: conv2's c3 read touches shorts 14,15
  // (= dword 7) of each row; cols 0-13 are fully written by conv1 and
  // cols 16-19 are never read. 84 rows.
  for (int i = lane; i < 84; i += 64) ((u32*)H1)[i * 10 + 7] = 0;

  // stage x: fp32 global -> bf16 LDS (padded rows)
  const float4* xg = (const float4*)(x + (size_t)img * 3072);
#pragma unroll
  for (int i = 0; i < 12; i++) {
    float4 v = xg[i * 64 + lane];
    short4v b;
    b.x = (short)f2bf(v.x); b.y = (short)f2bf(v.y);
    b.z = (short)f2bf(v.z); b.w = (short)f2bf(v.w);
    int idx = i * 256 + lane * 4;
    int c = idx & 31, r = idx >> 5;          // r = ci*32 + y
    *(short4v*)&X[r * XSTR + c] = b;
  }

  const float b1v = (mc < 6) ? c1b[mc] : 0.f;
  const float b2v = c2b[mc];

  // conv1 B frags resident in VGPRs: [ks][s]
  short8 B1f[4][4];
  {
    const short8* Bv = (const short8*)B1g;
#pragma unroll
    for (int s = 0; s < 4; s++)
#pragma unroll
      for (int ks = 0; ks < 4; ks++)
        B1f[ks][s] = Bv[((s * 4 + ks) * 16 + mc) * 4 + q];
  }

  // ---- conv1 + relu + pool -> H1 ----
  // R5: per (mt,ks) load the full row (32 shorts, 8x ds_read_b64) once;
  // the 7 overlapping a-window fragments come from register shuffles.
#pragma unroll
  for (int mt = 0; mt < 2; mt++) {
    short4v R[4][8];
#pragma unroll
    for (int ks = 0; ks < 4; ks++) {
      int o = ks * 4 + q;
      int dy = o / 3, ci = o - dy * 3;
      int y = mt * 16 + mc + dy;
      if (y > 31) y = 31;                 // discarded rows only; B is zero
      int rb = (ci * 32 + y) * XSTR;
#pragma unroll
      for (int j = 0; j < 8; j++)
        R[ks][j] = *(const short4v*)&X[rb + j * 4];
    }
#pragma unroll
    for (int a = 0; a < 7; a++) {
      f32x4 acc0 = zero4(), acc1 = zero4(), acc2 = zero4(), acc3 = zero4();
#pragma unroll
      for (int ks = 0; ks < 4; ks++) {
        short8 A = __builtin_shufflevector(R[ks][a], R[ks][a + 1],
                                           0, 1, 2, 3, 4, 5, 6, 7);
        acc0 = MFMA(A, B1f[ks][0], acc0);
        acc1 = MFMA(A, B1f[ks][1], acc1);
        acc2 = MFMA(A, B1f[ks][2], acc2);
        acc3 = MFMA(A, B1f[ks][3], acc3);
      }
#pragma unroll
      for (int rp = 0; rp < 2; rp++) {
        if (mt == 1 && q == 3) continue;    // oy >= 28 invalid
        int py = mt * 8 + q * 2 + rp;
        float v0 = fmaxf(fmaxf(acc0[2 * rp], acc0[2 * rp + 1]),
                         fmaxf(acc1[2 * rp], acc1[2 * rp + 1]));
        float v1 = fmaxf(fmaxf(acc2[2 * rp], acc2[2 * rp + 1]),
                         fmaxf(acc3[2 * rp], acc3[2 * rp + 1]));
        float p0 = fmaxf(v0 + b1v, 0.f);
        float p1 = fmaxf(v1 + b1v, 0.f);
        if (mc < 6) {
          u32 pk = ((u32)f2bf(p1) << 16) | (u32)f2bf(p0);
          *(u32*)&H1[(mc * 14 + py) * H1STR + a * 2] = pk;
        }
      }
    }
  }

  // conv2 B frags resident in VGPRs: [ks][s]
  short8 B2f[8][4];
  {
    const short8* Bv = (const short8*)B2g;
#pragma unroll
    for (int s = 0; s < 4; s++)
#pragma unroll
      for (int ks = 0; ks < 8; ks++)
        B2f[ks][s] = Bv[((s * 8 + ks) * 16 + mc) * 4 + q];
  }

  // ---- conv2 + relu + pool ----
  f32x4 a2[10];
#pragma unroll
  for (int i = 0; i < 10; i++) a2[i] = zero4();

#pragma unroll
  for (int ks = 0; ks < 8; ks++) {
    int o = ks * 4 + q;
    int dy = o / 6, ci = o - dy * 6;
    int y = mc + dy;
    if (y > 13) y = 13;                     // discarded rows only
    int base = (ci * 14 + y) * H1STR;
    short4v c0 = *(const short4v*)&H1[base];
    short4v c1 = *(const short4v*)&H1[base + 4];
    short4v c2 = *(const short4v*)&H1[base + 8];
    short4v c3 = *(const short4v*)&H1[base + 12];
    short8 A0 = __builtin_shufflevector(c0, c1, 0, 1, 2, 3, 4, 5, 6, 7);
    short8 A1 = __builtin_shufflevector(c1, c2, 0, 1, 2, 3, 4, 5, 6, 7);
    short8 A2 = __builtin_shufflevector(c2, c3, 0, 1, 2, 3, 4, 5, 6, 7);
    a2[0] = MFMA(A0, B2f[ks][0], a2[0]);
    a2[1] = MFMA(A0, B2f[ks][1], a2[1]);
    a2[2] = MFMA(A0, B2f[ks][2], a2[2]);
    a2[3] = MFMA(A0, B2f[ks][3], a2[3]);
    a2[4] = MFMA(A1, B2f[ks][0], a2[4]);
    a2[5] = MFMA(A1, B2f[ks][1], a2[5]);
    a2[6] = MFMA(A1, B2f[ks][2], a2[6]);
    a2[7] = MFMA(A1, B2f[ks][3], a2[7]);
    a2[8] = MFMA(A2, B2f[ks][0], a2[8]);
    a2[9] = MFMA(A2, B2f[ks][1], a2[9]);
  }

  // epilogue: relu+pool into LDS (reuse X region; x data is dead), then
  // coalesced dword store of the 800B h2 row.
#pragma unroll
  for (int a = 0; a < 3; a++) {
#pragma unroll
    for (int sp = 0; sp < 2; sp++) {
      if (a == 2 && sp == 1) continue;
      int px = a * 2 + sp;
      int ia = a * 4 + sp * 2;
#pragma unroll
      for (int rp = 0; rp < 2; rp++) {
        int oy = q * 4 + rp * 2;
        if (oy > 8) continue;
        int py = q * 2 + rp;
        float v = fmaxf(fmaxf(a2[ia][2 * rp], a2[ia][2 * rp + 1]),
                        fmaxf(a2[ia + 1][2 * rp], a2[ia + 1][2 * rp + 1]));
        float p = fmaxf(v + b2v, 0.f);
        X[mc * 25 + py * 5 + px] = (short)f2bf(p);
      }
    }
  }
  __asm__ volatile("s_waitcnt lgkmcnt(0)" ::: "memory");
  {
    const u32* Xu = (const u32*)X;
    u32* dst = (u32*)(h2g + (size_t)img * 400);
    for (int i = lane; i < 200; i += 64) dst[i] = Xu[i];
  }
}

// ---------------------------------------------------------------------------
// K3: FC stack, barrier-free: one wave owns 16 images end-to-end.
// Per-wave LDS (u16 units, 13440B): h3[16][136] @0, h4/h5[16][104] @2176,
// ys[16][176] @3840, probs (16 x float2) @6656.
// ---------------------------------------------------------------------------
#define FCW 6720
__global__ __launch_bounds__(256, 2)
void fc_kernel(const u16* __restrict__ h2g, const u16* __restrict__ F1,
               const u16* __restrict__ F2, const u16* __restrict__ EG,
               const u16* __restrict__ F4, const float* __restrict__ b1p,
               const float* __restrict__ b2p, const float* __restrict__ b4p,
               const float* __restrict__ eb, float* __restrict__ outp) {
  __shared__ __align__(16) u16 fcl[4][FCW];

  const int t = threadIdx.x;
  const int w = t >> 6, lane = t & 63, q = lane >> 4, mc = lane & 15;
  const size_t ib = (size_t)blockIdx.x * 64 + (size_t)w * 16;

  u16* h3 = fcl[w];            // [16][136]
  u16* h4 = fcl[w] + 2176;     // [16][104] (also h5 later)
  u16* ys = fcl[w] + 3840;     // [16][176]
  float2* probs = (float2*)(fcl[w] + 6656);

  // ---- fc1: A straight from global h2 (64B-granular), 8 n-tiles ----
  {
    short8 Af[13];
    const u16* arow = h2g + (ib + mc) * 400 + q * 8;
#pragma unroll
    for (int ks = 0; ks < 13; ks++)
      Af[ks] = *(const short8*)(arow + ks * 32);   // ks=12,q>=2 reads junk * B=0
    const short8* Bv = (const short8*)F1;
#pragma unroll
    for (int nt = 0; nt < 8; nt++) {
      f32x4 acc = zero4();
#pragma unroll
      for (int ks = 0; ks < 13; ks++)
        acc = MFMA(Af[ks], Bv[(nt * 16 + mc) * 52 + ks * 4 + q], acc);
      int n = nt * 16 + mc;
      float bias = b1p[n];
#pragma unroll
      for (int r = 0; r < 4; r++)
        h3[(q * 4 + r) * 136 + n] = f2bf(fmaxf(acc[r] + bias, 0.f));
    }
  }
  __asm__ volatile("s_waitcnt lgkmcnt(0)" ::: "memory");

  // ---- fc2: [16,128] x [128,96] ----
  {
    short8 Af[4];
#pragma unroll
    for (int ks = 0; ks < 4; ks++)
      Af[ks] = *(const short8*)&h3[mc * 136 + ks * 32 + q * 8];
    const short8* Bv = (const short8*)F2;
#pragma unroll
    for (int nt = 0; nt < 6; nt++) {
      f32x4 acc = zero4();
#pragma unroll
      for (int ks = 0; ks < 4; ks++)
        acc = MFMA(Af[ks], Bv[(nt * 16 + mc) * 16 + ks * 4 + q], acc);
      int n = nt * 16 + mc;
      float bias = b2p[n];
#pragma unroll
      for (int r = 0; r < 4; r++)
        h4[(q * 4 + r) * 104 + n] = f2bf(fmaxf(acc[r] + bias, 0.f));
    }
  }
  __asm__ volatile("s_waitcnt lgkmcnt(0)" ::: "memory");

  // ---- experts + gate: [16,96] x [96,176] ----
  {
    short8 Af[3];
#pragma unroll
    for (int ks = 0; ks < 3; ks++)
      Af[ks] = *(const short8*)&h4[mc * 104 + ks * 32 + q * 8];
    const short8* Bv = (const short8*)EG;
#pragma unroll
    for (int nt = 0; nt < 11; nt++) {
      f32x4 acc = zero4();
#pragma unroll
      for (int ks = 0; ks < 3; ks++)
        acc = MFMA(Af[ks], Bv[(nt * 16 + mc) * 12 + ks * 4 + q], acc);
      int n = nt * 16 + mc;
#pragma unroll
      for (int r = 0; r < 4; r++)
        ys[(q * 4 + r) * 176 + n] = f2bf(acc[r]);
    }
  }
  __asm__ volatile("s_waitcnt lgkmcnt(0)" ::: "memory");

  // softmax over gate logits (cols 168,169), one lane per image
  if (lane < 16) {
    float l0 = bf2f(ys[lane * 176 + 168]);
    float l1 = bf2f(ys[lane * 176 + 169]);
    float m = fmaxf(l0, l1);
    float e0 = __expf(l0 - m), e1 = __expf(l1 - m);
    float s = e0 + e1;
    probs[lane] = make_float2(e0 / s, e1 / s);
  }
  __asm__ volatile("s_waitcnt lgkmcnt(0)" ::: "memory");

  // combine into h5 (reuse h4 region), pad cols 84..95 = 0
  for (int i = lane; i < 16 * 84; i += 64) {
    int img = i / 84, h = i - img * 84;
    float2 p = probs[img];
    float y0 = bf2f(ys[img * 176 + h]) + eb[h];
    float y1 = bf2f(ys[img * 176 + 84 + h]) + eb[84 + h];
    h4[img * 104 + h] = f2bf(p.x * y0 + p.y * y1);
  }
  for (int i = lane; i < 16 * 12; i += 64)
    h4[(i / 12) * 104 + 84 + (i % 12)] = 0;
  __asm__ volatile("s_waitcnt lgkmcnt(0)" ::: "memory");

  // ---- fc4: [16,96] x [96,16] ----
  {
    short8 Af[3];
#pragma unroll
    for (int ks = 0; ks < 3; ks++)
      Af[ks] = *(const short8*)&h4[mc * 104 + ks * 32 + q * 8];
    const short8* Bv = (const short8*)F4;
    f32x4 acc = zero4();
#pragma unroll
    for (int ks = 0; ks < 3; ks++)
      acc = MFMA(Af[ks], Bv[mc * 12 + ks * 4 + q], acc);
    if (mc < 10) {
      float bias = b4p[mc];
#pragma unroll
      for (int r = 0; r < 4; r++)
        outp[(ib + q * 4 + r) * 10 + mc] = acc[r] + bias;
    }
  }
}

// ---------------------------------------------------------------------------
extern "C" void kernel_launch(void* const* d_in, const int* in_sizes, int n_in,
                              void* d_out, int out_size, void* d_ws, size_t ws_size,
                              hipStream_t stream) {
  const float* x   = (const float*)d_in[0];
  const float* c1w = (const float*)d_in[1];
  const float* c1b = (const float*)d_in[2];
  const float* c2w = (const float*)d_in[3];
  const float* c2b = (const float*)d_in[4];
  const float* f1w = (const float*)d_in[5];
  const float* f1b = (const float*)d_in[6];
  const float* f2w = (const float*)d_in[7];
  const float* f2b = (const float*)d_in[8];
  const float* gw  = (const float*)d_in[9];
  const float* ew  = (const float*)d_in[10];
  const float* ebp = (const float*)d_in[11];
  const float* f4w = (const float*)d_in[12];
  const float* f4b = (const float*)d_in[13];
  float* outp = (float*)d_out;

  char* ws = (char*)d_ws;
  u16* H2 = (u16*)(ws + OFF_H2);
  u16* B1 = (u16*)(ws + OFF_B1);
  u16* B2 = (u16*)(ws + OFF_B2);
  u16* F1 = (u16*)(ws + OFF_F1);
  u16* F2 = (u16*)(ws + OFF_F2);
  u16* EG = (u16*)(ws + OFF_EG);
  u16* F4 = (u16*)(ws + OFF_F4);
  float* b1p = (float*)(ws + OFF_B1P);
  float* b2p = (float*)(ws + OFF_B2P);
  float* b4p = (float*)(ws + OFF_B4P);

  prep_kernel<<<128, 256, 0, stream>>>(c1w, c2w, f1w, f2w, gw, ew, f4w,
                                       f1b, f2b, f4b,
                                       B1, B2, F1, F2, EG, F4, b1p, b2p, b4p);
  conv_kernel<<<8192, 256, 0, stream>>>(x, c1b, c2b, B1, B2, H2);
  fc_kernel<<<512, 256, 0, stream>>>(H2, F1, F2, EG, F4, b1p, b2p, b4p,
                                     ebp, outp);
}